// Round 10
// baseline (906.541 us; speedup 1.0000x reference)
//
#include <hip/hip_runtime.h>
#include <hip/hip_bf16.h>

// GCN 2-layer: z = A_n(relu(A_n(x@W1)+b1)@W2)+b2, A_n = D^-1/2 (A+I) D^-1/2
// N=100000, E=1600000, IN=768, HID=128, OUT=64.
// R7: CSR-by-dst on device; gather-sum agg; fused epilogues.       (990 us)
// R8: split-bf16 (hi/lo) MFMA GEMMs, 3 passes hh+hl+lh.            (895 us)
// R9/R10: vectorized agg — thread = (node, channel-quad), float4 gathers:
//     4x fewer load instrs, bit-exact same sum order per channel.

static constexpr int NN    = 100000;
static constexpr int NE    = 1600000;
static constexpr int C_IN  = 768;
static constexpr int C_HID = 128;
static constexpr int C_OUT = 64;
static constexpr int SCAN_B = 256;
static constexpr int NB_SCAN = (NN + SCAN_B - 1) / SCAN_B;   // 391

typedef __attribute__((ext_vector_type(8))) short bf16x8;
typedef __attribute__((ext_vector_type(4))) float f32x4;

__device__ __forceinline__ unsigned short f2bf(float f) {
    unsigned int x = __float_as_uint(f);
    unsigned int r = (x + 0x7fffu + ((x >> 16) & 1u)) >> 16;   // RNE
    return (unsigned short)r;
}
__device__ __forceinline__ float bf2f(unsigned short u) {
    return __uint_as_float(((unsigned int)u) << 16);
}

// ---------------- CSR build (unchanged from R7) ----------------
__global__ void k_zero_i(int* __restrict__ p, int n) {
    int i = blockIdx.x * blockDim.x + threadIdx.x;
    if (i < n) p[i] = 0;
}

__global__ void k_hist(const int* __restrict__ dst, int* __restrict__ cnt, int e) {
    int stride = gridDim.x * blockDim.x;
    for (int i = blockIdx.x * blockDim.x + threadIdx.x; i < e; i += stride)
        atomicAdd(&cnt[dst[i]], 1);
}

__global__ void k_dis(const int* __restrict__ cnt, float* __restrict__ dis, int n) {
    int i = blockIdx.x * blockDim.x + threadIdx.x;
    if (i < n) dis[i] = rsqrtf((float)cnt[i] + 1.0f);
}

__global__ __launch_bounds__(SCAN_B) void k_scan1(const int* __restrict__ cnt,
                                                  int* __restrict__ rp1,
                                                  int* __restrict__ bsum, int n) {
    __shared__ int sh[SCAN_B];
    int b = blockIdx.x, t = threadIdx.x, i = b * SCAN_B + t;
    sh[t] = (i < n) ? cnt[i] : 0;
    __syncthreads();
    for (int off = 1; off < SCAN_B; off <<= 1) {
        int u = (t >= off) ? sh[t - off] : 0;
        __syncthreads();
        sh[t] += u;
        __syncthreads();
    }
    if (i < n) rp1[i] = sh[t];
    if (t == SCAN_B - 1) bsum[b] = sh[t];
}

__global__ __launch_bounds__(512) void k_scan2(int* __restrict__ bsum, int nb) {
    __shared__ int sh[512];
    int t = threadIdx.x;
    sh[t] = (t < nb) ? bsum[t] : 0;
    __syncthreads();
    for (int off = 1; off < 512; off <<= 1) {
        int u = (t >= off) ? sh[t - off] : 0;
        __syncthreads();
        sh[t] += u;
        __syncthreads();
    }
    if (t < nb) bsum[t] = sh[t];
}

__global__ __launch_bounds__(SCAN_B) void k_scan3(int* __restrict__ rowptr,
                                                  const int* __restrict__ bsum,
                                                  int* __restrict__ cursor, int n) {
    int b = blockIdx.x, t = threadIdx.x, i = b * SCAN_B + t;
    if (b == 0 && t == 0) { rowptr[0] = 0; cursor[0] = 0; }
    if (i < n) {
        int v = rowptr[1 + i] + (b > 0 ? bsum[b - 1] : 0);
        rowptr[1 + i] = v;
        if (i + 1 < n) cursor[i + 1] = v;
    }
}

__global__ void k_scatter(const int* __restrict__ src, const int* __restrict__ dst,
                          int* __restrict__ cursor, int* __restrict__ csr, int e) {
    int stride = gridDim.x * blockDim.x;
    for (int i = blockIdx.x * blockDim.x + threadIdx.x; i < e; i += stride) {
        int p = atomicAdd(&cursor[dst[i]], 1);
        csr[p] = src[i];
    }
}

// ---------------- weight split: W[K][N] -> Wt_hi/Wt_lo[N][K] (bf16) ----------
template<int K, int N>
__global__ void k_splitW(const float* __restrict__ W,
                         unsigned short* __restrict__ th,
                         unsigned short* __restrict__ tl) {
    int idx = blockIdx.x * blockDim.x + threadIdx.x;
    if (idx < K * N) {
        int k = idx / N, n = idx - k * N;
        float a = W[idx];
        unsigned short h = f2bf(a);
        th[n * K + k] = h;
        tl[n * K + k] = f2bf(a - bf2f(h));
    }
}

// ---------------- split-bf16 MFMA GEMM (unchanged from R8) ----------------
template<int K, int N_>
__global__ __launch_bounds__(256) void k_gemm_mfma(const float* __restrict__ A,
                                                   const unsigned short* __restrict__ Bh,
                                                   const unsigned short* __restrict__ Bl,
                                                   float* __restrict__ C,
                                                   const float* __restrict__ dis, int M) {
    constexpr int RT = (N_ == 128) ? 4 : 2;
    constexpr int CT = 2;
    constexpr int LDK = 40;                       // padded k-stride (80 B)

    __shared__ unsigned short sAh[64][LDK], sAl[64][LDK];
    __shared__ unsigned short sBh[N_][LDK], sBl[N_][LDK];

    const int tid  = threadIdx.x;
    const int w    = tid >> 6;
    const int lane = tid & 63;
    const int lr   = lane & 15;
    const int ls   = lane >> 4;
    const int row0 = blockIdx.x * 64;

    const int row_base = (N_ == 128) ? 0 : (w >> 1) * 32;
    const int col_base = (N_ == 128) ? w * 32 : (w & 1) * 32;

    f32x4 acc[RT][CT];
    #pragma unroll
    for (int i = 0; i < RT; ++i)
        #pragma unroll
        for (int j = 0; j < CT; ++j) acc[i][j] = (f32x4){0.f, 0.f, 0.f, 0.f};

    for (int k0 = 0; k0 < K; k0 += 32) {
        #pragma unroll
        for (int l = 0; l < 2; ++l) {
            int f   = tid + l * 256;
            int row = f >> 3;
            int kc  = (f & 7) << 2;
            int gr  = row0 + row;
            float4 v = make_float4(0.f, 0.f, 0.f, 0.f);
            if (gr < M) v = *(const float4*)(A + gr * K + k0 + kc);
            unsigned short h0 = f2bf(v.x), h1 = f2bf(v.y), h2 = f2bf(v.z), h3 = f2bf(v.w);
            *(short4*)&sAh[row][kc] = make_short4(h0, h1, h2, h3);
            *(short4*)&sAl[row][kc] = make_short4(f2bf(v.x - bf2f(h0)), f2bf(v.y - bf2f(h1)),
                                                  f2bf(v.z - bf2f(h2)), f2bf(v.w - bf2f(h3)));
        }
        #pragma unroll
        for (int l = 0; l < (N_ * 4) / 256; ++l) {
            int c   = tid + l * 256;
            int col = c >> 2;
            int kc8 = (c & 3) * 8;
            *(uint4*)&sBh[col][kc8] = *(const uint4*)&Bh[col * K + k0 + kc8];
            *(uint4*)&sBl[col][kc8] = *(const uint4*)&Bl[col * K + k0 + kc8];
        }
        __syncthreads();

        bf16x8 ah[RT], al[RT], bh[CT], bl[CT];
        #pragma unroll
        for (int rt = 0; rt < RT; ++rt) {
            int arow = row_base + rt * 16 + lr;
            ah[rt] = *(const bf16x8*)&sAh[arow][ls * 8];
            al[rt] = *(const bf16x8*)&sAl[arow][ls * 8];
        }
        #pragma unroll
        for (int ct = 0; ct < CT; ++ct) {
            int bcol = col_base + ct * 16 + lr;
            bh[ct] = *(const bf16x8*)&sBh[bcol][ls * 8];
            bl[ct] = *(const bf16x8*)&sBl[bcol][ls * 8];
        }
        #pragma unroll
        for (int rt = 0; rt < RT; ++rt)
            #pragma unroll
            for (int ct = 0; ct < CT; ++ct) {
                acc[rt][ct] = __builtin_amdgcn_mfma_f32_16x16x32_bf16(ah[rt], bh[ct], acc[rt][ct], 0, 0, 0);
                acc[rt][ct] = __builtin_amdgcn_mfma_f32_16x16x32_bf16(ah[rt], bl[ct], acc[rt][ct], 0, 0, 0);
                acc[rt][ct] = __builtin_amdgcn_mfma_f32_16x16x32_bf16(al[rt], bh[ct], acc[rt][ct], 0, 0, 0);
            }
        __syncthreads();
    }

    #pragma unroll
    for (int rt = 0; rt < RT; ++rt) {
        #pragma unroll
        for (int r = 0; r < 4; ++r) {
            int grow = row0 + row_base + rt * 16 + ls * 4 + r;
            if (grow < M) {
                float dn = dis[grow];
                #pragma unroll
                for (int ct = 0; ct < CT; ++ct) {
                    int gcol = col_base + ct * 16 + lr;
                    C[grow * N_ + gcol] = acc[rt][ct][r] * dn;
                }
            }
        }
    }
}

// ---------------- vectorized aggregation (R9) ----------------
// thread = (node d, channel-quad q). Same per-channel add order as R7/R8
// (self, then edge quads f0+f1 / f2+f3, then tail) -> bit-exact output.
template<int C, bool RELU>
__global__ __launch_bounds__(256) void k_aggv(const int* __restrict__ rowptr,
                                              const int* __restrict__ csr,
                                              const float* __restrict__ feat,
                                              const float* __restrict__ dis,
                                              const float* __restrict__ bias,
                                              float* __restrict__ out, int nn) {
    constexpr int CQ  = C / 4;        // quads per row: 32 (C=128) or 16 (C=64)
    constexpr int NPB = 256 / CQ;     // nodes per block: 8 or 16
    const int d = blockIdx.x * NPB + threadIdx.y;
    if (d >= nn) return;
    const int q = threadIdx.x;

    const int beg = rowptr[d], end = rowptr[d + 1];
    float4 sum = *(const float4*)(feat + d * C + q * 4);   // self-loop term
    int e = beg;
    for (; e + 4 <= end; e += 4) {
        int s0 = csr[e], s1 = csr[e + 1], s2 = csr[e + 2], s3 = csr[e + 3];
        float4 f0 = *(const float4*)(feat + s0 * C + q * 4);
        float4 f1 = *(const float4*)(feat + s1 * C + q * 4);
        float4 f2 = *(const float4*)(feat + s2 * C + q * 4);
        float4 f3 = *(const float4*)(feat + s3 * C + q * 4);
        sum.x += (f0.x + f1.x) + (f2.x + f3.x);
        sum.y += (f0.y + f1.y) + (f2.y + f3.y);
        sum.z += (f0.z + f1.z) + (f2.z + f3.z);
        sum.w += (f0.w + f1.w) + (f2.w + f3.w);
    }
    for (; e < end; ++e) {
        float4 f = *(const float4*)(feat + csr[e] * C + q * 4);
        sum.x += f.x; sum.y += f.y; sum.z += f.z; sum.w += f.w;
    }
    const float dn = dis[d];
    float4 b4 = *(const float4*)(bias + q * 4);
    float4 r;
    r.x = sum.x * dn + b4.x; r.y = sum.y * dn + b4.y;
    r.z = sum.z * dn + b4.z; r.w = sum.w * dn + b4.w;
    if (RELU) {
        r.x = fmaxf(r.x, 0.f); r.y = fmaxf(r.y, 0.f);
        r.z = fmaxf(r.z, 0.f); r.w = fmaxf(r.w, 0.f);
    }
    *(float4*)(out + d * C + q * 4) = r;
}

extern "C" void kernel_launch(void* const* d_in, const int* in_sizes, int n_in,
                              void* d_out, int out_size, void* d_ws, size_t ws_size,
                              hipStream_t stream) {
    const float* x  = (const float*)d_in[0];
    const int*   ei = (const int*)d_in[1];
    const float* W1 = (const float*)d_in[2];
    const float* b1 = (const float*)d_in[3];
    const float* W2 = (const float*)d_in[4];
    const float* b2 = (const float*)d_in[5];
    float* z = (float*)d_out;

    char* ws = (char*)d_ws;
    float* dis    = (float*)(ws + 0);
    int*   cnt    = (int*)  (ws + 524288);             // reused as cursor
    int*   rowptr = (int*)  (ws + 1048576);
    int*   bsum   = (int*)  (ws + 1572864);
    int*   csr    = (int*)  (ws + 2097152);            // 6.4 MB
    unsigned short* w1h = (unsigned short*)(ws + 8912896);
    unsigned short* w1l = (unsigned short*)(ws + 9109504);
    unsigned short* w2h = (unsigned short*)(ws + 9306112);
    unsigned short* w2l = (unsigned short*)(ws + 9322496);
    float* xw     = (float*)(ws + 9437184);            // 51.2 MB (reused as hw)
    float* h      = (float*)(ws + 60817408);           // 51.2 MB

    const int* src = ei;
    const int* dst = ei + NE;

    // ---- degree + norm + CSR build ----
    k_zero_i<<<(NN + 255) / 256, 256, 0, stream>>>(cnt, NN);
    k_hist<<<4096, 256, 0, stream>>>(dst, cnt, NE);
    k_dis<<<(NN + 255) / 256, 256, 0, stream>>>(cnt, dis, NN);
    k_scan1<<<NB_SCAN, SCAN_B, 0, stream>>>(cnt, rowptr + 1, bsum, NN);
    k_scan2<<<1, 512, 0, stream>>>(bsum, NB_SCAN);
    k_scan3<<<NB_SCAN, SCAN_B, 0, stream>>>(rowptr, bsum, cnt /*cursor*/, NN);
    k_scatter<<<4096, 256, 0, stream>>>(src, dst, cnt /*cursor*/, csr, NE);

    // ---- weight split (bf16 hi/lo, transposed) ----
    k_splitW<C_IN, C_HID><<<(C_IN * C_HID + 255) / 256, 256, 0, stream>>>(W1, w1h, w1l);
    k_splitW<C_HID, C_OUT><<<(C_HID * C_OUT + 255) / 256, 256, 0, stream>>>(W2, w2h, w2l);

    // ---- layer 1 ----
    k_gemm_mfma<C_IN, C_HID><<<(NN + 63) / 64, 256, 0, stream>>>(x, w1h, w1l, xw, dis, NN);
    {
        dim3 blk(C_HID / 4, 256 / (C_HID / 4));
        int npb = 256 / (C_HID / 4);
        k_aggv<C_HID, true><<<(NN + npb - 1) / npb, blk, 0, stream>>>(rowptr, csr, xw, dis, b1, h, NN);
    }

    // ---- layer 2 ----
    float* hw = xw;
    k_gemm_mfma<C_HID, C_OUT><<<(NN + 63) / 64, 256, 0, stream>>>(h, w2h, w2l, hw, dis, NN);
    {
        dim3 blk(C_OUT / 4, 256 / (C_OUT / 4));
        int npb = 256 / (C_OUT / 4);
        k_aggv<C_OUT, false><<<(NN + npb - 1) / npb, blk, 0, stream>>>(rowptr, csr, hw, dis, b2, z, NN);
    }
}

// Round 11
// 805.439 us; speedup vs baseline: 1.1255x; 1.1255x over previous
//
#include <hip/hip_runtime.h>
#include <hip/hip_bf16.h>

// GCN 2-layer: z = A_n(relu(A_n(x@W1)+b1)@W2)+b2, A_n = D^-1/2 (A+I) D^-1/2
// N=100000, E=1600000, IN=768, HID=128, OUT=64.
// R7: CSR-by-dst on device; gather-sum agg; fused epilogues.        (990 us)
// R8: split-bf16 (hi/lo) MFMA GEMMs, 3 passes hh+hl+lh.             (895 us)
// R9/R10: float4 agg — NULL result: agg is bytes-bound, not issue-bound.
// R11: inter-layer feats in fp16 (xw, h) — halves agg gather traffic,
//      halves gemm writes & gemm2 A-reads. fp16 = bf16_hi+bf16_lo exactly,
//      so split-bf16 GEMM structure unchanged. Adds ~5e-4 rel rounding.

static constexpr int NN    = 100000;
static constexpr int NE    = 1600000;
static constexpr int C_IN  = 768;
static constexpr int C_HID = 128;
static constexpr int C_OUT = 64;
static constexpr int SCAN_B = 256;
static constexpr int NB_SCAN = (NN + SCAN_B - 1) / SCAN_B;   // 391

typedef __attribute__((ext_vector_type(8))) short bf16x8;
typedef __attribute__((ext_vector_type(4))) float f32x4;
typedef __attribute__((ext_vector_type(8))) _Float16 f16x8;

__device__ __forceinline__ unsigned short f2bf(float f) {
    unsigned int x = __float_as_uint(f);
    unsigned int r = (x + 0x7fffu + ((x >> 16) & 1u)) >> 16;   // RNE
    return (unsigned short)r;
}
__device__ __forceinline__ float bf2f(unsigned short u) {
    return __uint_as_float(((unsigned int)u) << 16);
}

// ---------------- CSR build (unchanged from R7) ----------------
__global__ void k_zero_i(int* __restrict__ p, int n) {
    int i = blockIdx.x * blockDim.x + threadIdx.x;
    if (i < n) p[i] = 0;
}

__global__ void k_hist(const int* __restrict__ dst, int* __restrict__ cnt, int e) {
    int stride = gridDim.x * blockDim.x;
    for (int i = blockIdx.x * blockDim.x + threadIdx.x; i < e; i += stride)
        atomicAdd(&cnt[dst[i]], 1);
}

__global__ void k_dis(const int* __restrict__ cnt, float* __restrict__ dis, int n) {
    int i = blockIdx.x * blockDim.x + threadIdx.x;
    if (i < n) dis[i] = rsqrtf((float)cnt[i] + 1.0f);
}

__global__ __launch_bounds__(SCAN_B) void k_scan1(const int* __restrict__ cnt,
                                                  int* __restrict__ rp1,
                                                  int* __restrict__ bsum, int n) {
    __shared__ int sh[SCAN_B];
    int b = blockIdx.x, t = threadIdx.x, i = b * SCAN_B + t;
    sh[t] = (i < n) ? cnt[i] : 0;
    __syncthreads();
    for (int off = 1; off < SCAN_B; off <<= 1) {
        int u = (t >= off) ? sh[t - off] : 0;
        __syncthreads();
        sh[t] += u;
        __syncthreads();
    }
    if (i < n) rp1[i] = sh[t];
    if (t == SCAN_B - 1) bsum[b] = sh[t];
}

__global__ __launch_bounds__(512) void k_scan2(int* __restrict__ bsum, int nb) {
    __shared__ int sh[512];
    int t = threadIdx.x;
    sh[t] = (t < nb) ? bsum[t] : 0;
    __syncthreads();
    for (int off = 1; off < 512; off <<= 1) {
        int u = (t >= off) ? sh[t - off] : 0;
        __syncthreads();
        sh[t] += u;
        __syncthreads();
    }
    if (t < nb) bsum[t] = sh[t];
}

__global__ __launch_bounds__(SCAN_B) void k_scan3(int* __restrict__ rowptr,
                                                  const int* __restrict__ bsum,
                                                  int* __restrict__ cursor, int n) {
    int b = blockIdx.x, t = threadIdx.x, i = b * SCAN_B + t;
    if (b == 0 && t == 0) { rowptr[0] = 0; cursor[0] = 0; }
    if (i < n) {
        int v = rowptr[1 + i] + (b > 0 ? bsum[b - 1] : 0);
        rowptr[1 + i] = v;
        if (i + 1 < n) cursor[i + 1] = v;
    }
}

__global__ void k_scatter(const int* __restrict__ src, const int* __restrict__ dst,
                          int* __restrict__ cursor, int* __restrict__ csr, int e) {
    int stride = gridDim.x * blockDim.x;
    for (int i = blockIdx.x * blockDim.x + threadIdx.x; i < e; i += stride) {
        int p = atomicAdd(&cursor[dst[i]], 1);
        csr[p] = src[i];
    }
}

// ---------------- weight split: W[K][N] -> Wt_hi/Wt_lo[N][K] (bf16) ----------
template<int K, int N>
__global__ void k_splitW(const float* __restrict__ W,
                         unsigned short* __restrict__ th,
                         unsigned short* __restrict__ tl) {
    int idx = blockIdx.x * blockDim.x + threadIdx.x;
    if (idx < K * N) {
        int k = idx / N, n = idx - k * N;
        float a = W[idx];
        unsigned short h = f2bf(a);
        th[n * K + k] = h;
        tl[n * K + k] = f2bf(a - bf2f(h));
    }
}

// ---------------- split-bf16 MFMA GEMM, fp16 output ----------------
// C16[M,N_] = fp16( (A[M,K] @ B[K,N_]) * dis[row] ), B pre-split bf16 [N_][K].
// A is fp32 (A16=false) or fp16 (A16=true; fp16 = bf16hi+bf16lo exactly).
template<int K, int N_, bool A16>
__global__ __launch_bounds__(256) void k_gemm_mfma(const void* __restrict__ Ap,
                                                   const unsigned short* __restrict__ Bh,
                                                   const unsigned short* __restrict__ Bl,
                                                   _Float16* __restrict__ C,
                                                   const float* __restrict__ dis, int M) {
    constexpr int RT = (N_ == 128) ? 4 : 2;
    constexpr int CT = 2;
    constexpr int LDK = 40;                       // padded k-stride (80 B)

    __shared__ unsigned short sAh[64][LDK], sAl[64][LDK];
    __shared__ unsigned short sBh[N_][LDK], sBl[N_][LDK];

    const int tid  = threadIdx.x;
    const int w    = tid >> 6;
    const int lane = tid & 63;
    const int lr   = lane & 15;
    const int ls   = lane >> 4;
    const int row0 = blockIdx.x * 64;

    const int row_base = (N_ == 128) ? 0 : (w >> 1) * 32;
    const int col_base = (N_ == 128) ? w * 32 : (w & 1) * 32;

    f32x4 acc[RT][CT];
    #pragma unroll
    for (int i = 0; i < RT; ++i)
        #pragma unroll
        for (int j = 0; j < CT; ++j) acc[i][j] = (f32x4){0.f, 0.f, 0.f, 0.f};

    for (int k0 = 0; k0 < K; k0 += 32) {
        // ---- stage A: 64 rows x 32 k -> hi/lo bf16 ----
        if constexpr (!A16) {
            const float* A = (const float*)Ap;
            #pragma unroll
            for (int l = 0; l < 2; ++l) {
                int f   = tid + l * 256;
                int row = f >> 3;
                int kc  = (f & 7) << 2;
                int gr  = row0 + row;
                float4 v = make_float4(0.f, 0.f, 0.f, 0.f);
                if (gr < M) v = *(const float4*)(A + (size_t)gr * K + k0 + kc);
                unsigned short h0 = f2bf(v.x), h1 = f2bf(v.y), h2 = f2bf(v.z), h3 = f2bf(v.w);
                *(short4*)&sAh[row][kc] = make_short4(h0, h1, h2, h3);
                *(short4*)&sAl[row][kc] = make_short4(f2bf(v.x - bf2f(h0)), f2bf(v.y - bf2f(h1)),
                                                      f2bf(v.z - bf2f(h2)), f2bf(v.w - bf2f(h3)));
            }
        } else {
            const _Float16* A = (const _Float16*)Ap;
            int f   = tid;                        // 2048 elems / 8 per thread
            int row = f >> 2;
            int kc  = (f & 3) * 8;
            int gr  = row0 + row;
            f16x8 v;
            #pragma unroll
            for (int j = 0; j < 8; ++j) v[j] = (_Float16)0.f;
            if (gr < M) v = *(const f16x8*)(A + (size_t)gr * K + k0 + kc);
            unsigned short hh[8], ll[8];
            #pragma unroll
            for (int j = 0; j < 8; ++j) {
                float xv = (float)v[j];
                hh[j] = f2bf(xv);
                ll[j] = f2bf(xv - bf2f(hh[j]));
            }
            *(short4*)&sAh[row][kc]     = make_short4(hh[0], hh[1], hh[2], hh[3]);
            *(short4*)&sAh[row][kc + 4] = make_short4(hh[4], hh[5], hh[6], hh[7]);
            *(short4*)&sAl[row][kc]     = make_short4(ll[0], ll[1], ll[2], ll[3]);
            *(short4*)&sAl[row][kc + 4] = make_short4(ll[4], ll[5], ll[6], ll[7]);
        }
        // ---- stage B ----
        #pragma unroll
        for (int l = 0; l < (N_ * 4) / 256; ++l) {
            int c   = tid + l * 256;
            int col = c >> 2;
            int kc8 = (c & 3) * 8;
            *(uint4*)&sBh[col][kc8] = *(const uint4*)&Bh[col * K + k0 + kc8];
            *(uint4*)&sBl[col][kc8] = *(const uint4*)&Bl[col * K + k0 + kc8];
        }
        __syncthreads();

        bf16x8 ah[RT], al[RT], bh[CT], bl[CT];
        #pragma unroll
        for (int rt = 0; rt < RT; ++rt) {
            int arow = row_base + rt * 16 + lr;
            ah[rt] = *(const bf16x8*)&sAh[arow][ls * 8];
            al[rt] = *(const bf16x8*)&sAl[arow][ls * 8];
        }
        #pragma unroll
        for (int ct = 0; ct < CT; ++ct) {
            int bcol = col_base + ct * 16 + lr;
            bh[ct] = *(const bf16x8*)&sBh[bcol][ls * 8];
            bl[ct] = *(const bf16x8*)&sBl[bcol][ls * 8];
        }
        #pragma unroll
        for (int rt = 0; rt < RT; ++rt)
            #pragma unroll
            for (int ct = 0; ct < CT; ++ct) {
                acc[rt][ct] = __builtin_amdgcn_mfma_f32_16x16x32_bf16(ah[rt], bh[ct], acc[rt][ct], 0, 0, 0);
                acc[rt][ct] = __builtin_amdgcn_mfma_f32_16x16x32_bf16(ah[rt], bl[ct], acc[rt][ct], 0, 0, 0);
                acc[rt][ct] = __builtin_amdgcn_mfma_f32_16x16x32_bf16(al[rt], bh[ct], acc[rt][ct], 0, 0, 0);
            }
        __syncthreads();
    }

    #pragma unroll
    for (int rt = 0; rt < RT; ++rt) {
        #pragma unroll
        for (int r = 0; r < 4; ++r) {
            int grow = row0 + row_base + rt * 16 + ls * 4 + r;
            if (grow < M) {
                float dn = dis[grow];
                #pragma unroll
                for (int ct = 0; ct < CT; ++ct) {
                    int gcol = col_base + ct * 16 + lr;
                    C[(size_t)grow * N_ + gcol] = (_Float16)(acc[rt][ct][r] * dn);
                }
            }
        }
    }
}

// ---------------- fp16-gather aggregation ----------------
// thread = (node d, channel-octet o): 16B gathers, fp32 accumulate.
// out fp16 (inter-layer h) or fp32 (final z).
template<int C, bool RELU, bool OUT16>
__global__ __launch_bounds__(256) void k_aggh(const int* __restrict__ rowptr,
                                              const int* __restrict__ csr,
                                              const _Float16* __restrict__ feat,
                                              const float* __restrict__ dis,
                                              const float* __restrict__ bias,
                                              void* __restrict__ outp, int nn) {
    constexpr int OPR = C / 8;        // octets per row: 16 (C=128) or 8 (C=64)
    constexpr int NPB = 256 / OPR;    // nodes per block: 16 or 32
    const int d = blockIdx.x * NPB + threadIdx.y;
    if (d >= nn) return;
    const int o = threadIdx.x;

    const int beg = rowptr[d], end = rowptr[d + 1];
    float s[8];
    {
        f16x8 v = *(const f16x8*)(feat + (size_t)d * C + o * 8);   // self-loop
        #pragma unroll
        for (int j = 0; j < 8; ++j) s[j] = (float)v[j];
    }
    int e = beg;
    for (; e + 4 <= end; e += 4) {
        int s0 = csr[e], s1 = csr[e + 1], s2 = csr[e + 2], s3 = csr[e + 3];
        f16x8 f0 = *(const f16x8*)(feat + (size_t)s0 * C + o * 8);
        f16x8 f1 = *(const f16x8*)(feat + (size_t)s1 * C + o * 8);
        f16x8 f2 = *(const f16x8*)(feat + (size_t)s2 * C + o * 8);
        f16x8 f3 = *(const f16x8*)(feat + (size_t)s3 * C + o * 8);
        #pragma unroll
        for (int j = 0; j < 8; ++j)
            s[j] += ((float)f0[j] + (float)f1[j]) + ((float)f2[j] + (float)f3[j]);
    }
    for (; e < end; ++e) {
        f16x8 f = *(const f16x8*)(feat + (size_t)csr[e] * C + o * 8);
        #pragma unroll
        for (int j = 0; j < 8; ++j) s[j] += (float)f[j];
    }
    const float dn = dis[d];
    float r[8];
    #pragma unroll
    for (int j = 0; j < 8; ++j) {
        r[j] = s[j] * dn + bias[o * 8 + j];
        if (RELU) r[j] = fmaxf(r[j], 0.f);
    }
    if constexpr (OUT16) {
        _Float16* out = (_Float16*)outp;
        f16x8 pv;
        #pragma unroll
        for (int j = 0; j < 8; ++j) pv[j] = (_Float16)r[j];
        *(f16x8*)(out + (size_t)d * C + o * 8) = pv;
    } else {
        float* out = (float*)outp;
        *(float4*)(out + (size_t)d * C + o * 8)     = make_float4(r[0], r[1], r[2], r[3]);
        *(float4*)(out + (size_t)d * C + o * 8 + 4) = make_float4(r[4], r[5], r[6], r[7]);
    }
}

extern "C" void kernel_launch(void* const* d_in, const int* in_sizes, int n_in,
                              void* d_out, int out_size, void* d_ws, size_t ws_size,
                              hipStream_t stream) {
    const float* x  = (const float*)d_in[0];
    const int*   ei = (const int*)d_in[1];
    const float* W1 = (const float*)d_in[2];
    const float* b1 = (const float*)d_in[3];
    const float* W2 = (const float*)d_in[4];
    const float* b2 = (const float*)d_in[5];
    float* z = (float*)d_out;

    char* ws = (char*)d_ws;
    float* dis    = (float*)(ws + 0);
    int*   cnt    = (int*)  (ws + 524288);             // reused as cursor
    int*   rowptr = (int*)  (ws + 1048576);
    int*   bsum   = (int*)  (ws + 1572864);
    int*   csr    = (int*)  (ws + 2097152);            // 6.4 MB
    unsigned short* w1h = (unsigned short*)(ws + 8912896);
    unsigned short* w1l = (unsigned short*)(ws + 9109504);
    unsigned short* w2h = (unsigned short*)(ws + 9306112);
    unsigned short* w2l = (unsigned short*)(ws + 9322496);
    _Float16* xw16 = (_Float16*)(ws + 9437184);        // 25.6 MB (reused as hw16)
    _Float16* h16  = (_Float16*)(ws + 41943040);       // 25.6 MB

    const int* src = ei;
    const int* dst = ei + NE;

    // ---- degree + norm + CSR build ----
    k_zero_i<<<(NN + 255) / 256, 256, 0, stream>>>(cnt, NN);
    k_hist<<<4096, 256, 0, stream>>>(dst, cnt, NE);
    k_dis<<<(NN + 255) / 256, 256, 0, stream>>>(cnt, dis, NN);
    k_scan1<<<NB_SCAN, SCAN_B, 0, stream>>>(cnt, rowptr + 1, bsum, NN);
    k_scan2<<<1, 512, 0, stream>>>(bsum, NB_SCAN);
    k_scan3<<<NB_SCAN, SCAN_B, 0, stream>>>(rowptr, bsum, cnt /*cursor*/, NN);
    k_scatter<<<4096, 256, 0, stream>>>(src, dst, cnt /*cursor*/, csr, NE);

    // ---- weight split (bf16 hi/lo, transposed) ----
    k_splitW<C_IN, C_HID><<<(C_IN * C_HID + 255) / 256, 256, 0, stream>>>(W1, w1h, w1l);
    k_splitW<C_HID, C_OUT><<<(C_HID * C_OUT + 255) / 256, 256, 0, stream>>>(W2, w2h, w2l);

    // ---- layer 1 ----
    k_gemm_mfma<C_IN, C_HID, false><<<(NN + 63) / 64, 256, 0, stream>>>(x, w1h, w1l, xw16, dis, NN);
    {
        constexpr int NPB = 256 / (C_HID / 8);         // 16
        dim3 blk(C_HID / 8, NPB);
        k_aggh<C_HID, true, true><<<(NN + NPB - 1) / NPB, blk, 0, stream>>>(rowptr, csr, xw16, dis, b1, h16, NN);
    }

    // ---- layer 2 ----
    _Float16* hw16 = xw16;
    k_gemm_mfma<C_HID, C_OUT, true><<<(NN + 63) / 64, 256, 0, stream>>>(h16, w2h, w2l, hw16, dis, NN);
    {
        constexpr int NPB = 256 / (C_OUT / 8);         // 32
        dim3 blk(C_OUT / 8, NPB);
        k_aggh<C_OUT, false, false><<<(NN + NPB - 1) / NPB, blk, 0, stream>>>(rowptr, csr, hw16, dis, b2, z, NN);
    }
}